// Round 6
// baseline (183.906 us; speedup 1.0000x reference)
//
#include <hip/hip_runtime.h>
#include <hip/hip_bf16.h>

#define NN 50000
#define NE 1600000
#define DD 128
#define NPB 64                 // nodes per bucket (dst>>6)
#define NBK 782                // ceil(NN/64)
#define MAXB 2560              // bucket slab capacity (mean 2048, +11 sigma)
#define QSLAB 640              // quarter-slab capacity (MAXB/4)
#define NSPL 4                 // sortagg split factor (blocks per bucket)
#define CHUNK 3072             // edges per convscatter block (2 blocks/CU shape)
#define NCB 521                // ceil(NE/CHUNK)
#define WS 136                 // gemm LDS row stride (bf16 elems): balanced banks
#define GCS 16                 // gcursor stride (ints): 1 counter per 64B line

typedef __attribute__((ext_vector_type(8))) short short8;
typedef __attribute__((ext_vector_type(4))) float f32x4;

__device__ inline unsigned short to_bf16(float v) {
    __hip_bfloat16 h = __float2bfloat16(v);
    return __builtin_bit_cast(unsigned short, h);
}
__device__ inline float bf2f(unsigned short u) {
    return __uint_as_float((unsigned)u << 16);
}

// ---- phase 1: x->fp8 convert + W/B->bf16 convert + bucket-sorted scatter ----
// 521 blocks x 1024 thr (~2 blocks/CU). gcursor is line-padded (stride 16) and
// its atomic is issued right after the histogram barrier so the RMW latency
// overlaps the scan instead of stalling at the gb-store barrier drain.
__global__ __launch_bounds__(1024) void convscatter_k(const int* __restrict__ ei,
                                                      const float* __restrict__ x,
                                                      const float* __restrict__ W,
                                                      const float* __restrict__ Bm,
                                                      unsigned int* __restrict__ xb,
                                                      unsigned short* __restrict__ Wbf,
                                                      unsigned short* __restrict__ Bbf,
                                                      int* __restrict__ gcursor,
                                                      int* __restrict__ ebuf) {
    __shared__ int stg[CHUNK];        // 12 KB
    __shared__ int h[NBK];
    __shared__ int lbase[NBK];
    __shared__ int gb[NBK];
    __shared__ int hcur[NBK];
    __shared__ int wsum[16], wbase[16];
    const int t = threadIdx.x;
    const int lane = t & 63, wv = t >> 6;
    const int e0 = blockIdx.x * CHUNK;
    const int ec = min(CHUNK, NE - e0);

    for (int i = t; i < NBK; i += 1024) h[i] = 0;
    __syncthreads();

    unsigned int w2[3];
    #pragma unroll
    for (int u = 0; u < 3; ++u) {
        int i = u * 1024 + t;
        if (i < ec) {
            int src = ei[e0 + i];
            int dst = ei[NE + e0 + i];
            int b = dst >> 6;
            w2[u] = ((unsigned)b << 22) | ((unsigned)src << 6) | (unsigned)(dst & 63);
            atomicAdd(&h[b], 1);
        } else w2[u] = 0xFFFFFFFFu;
    }

    // independent: convert x (fp32) -> xb (packed 4x fp8-e4m3 per uint)
    {
        int gid = blockIdx.x * 1024 + t;
        const int total4 = NN * DD / 4;  // 1.6M float4 -> 1.6M uints
        for (int i = gid; i < total4; i += NCB * 1024) {
            float4 v = ((const float4*)x)[i];
            int p = __builtin_amdgcn_cvt_pk_fp8_f32(v.x, v.y, 0, false);
            p = __builtin_amdgcn_cvt_pk_fp8_f32(v.z, v.w, p, true);
            xb[i] = (unsigned)p;
        }
    }
    // independent: convert W,B (fp32) -> bf16, done by the underloaded last block
    if (blockIdx.x == NCB - 1) {
        for (int i = t; i < DD * DD / 4; i += 1024) {
            float4 w4 = ((const float4*)W)[i];
            float4 b4 = ((const float4*)Bm)[i];
            ushort4 wp, bp;
            wp.x = to_bf16(w4.x); wp.y = to_bf16(w4.y); wp.z = to_bf16(w4.z); wp.w = to_bf16(w4.w);
            bp.x = to_bf16(b4.x); bp.y = to_bf16(b4.y); bp.z = to_bf16(b4.z); bp.w = to_bf16(b4.w);
            ((ushort4*)Wbf)[i] = wp;
            ((ushort4*)Bbf)[i] = bp;
        }
    }
    __syncthreads();

    // slab-space allocation: issue the global atomic NOW (h complete), consume
    // its result only after the scan -> latency hidden under the scan barriers.
    int v = (t < NBK) ? h[t] : 0;
    int gpos = 0;
    if (v > 0) gpos = atomicAdd(&gcursor[t << 4], v);

    // hierarchical scan over NBK buckets (1 per thread, 2 barriers)
    int s = v;
    #pragma unroll
    for (int o = 1; o < 64; o <<= 1) {
        int u = __shfl_up(s, o);
        if (lane >= o) s += u;
    }
    if (lane == 63) wsum[wv] = s;
    __syncthreads();
    if (wv == 0 && lane < 16) {
        int bv = wsum[lane];
        int bs = bv;
        #pragma unroll
        for (int o = 1; o < 16; o <<= 1) {
            int u = __shfl_up(bs, o);
            if (lane >= o) bs += u;
        }
        wbase[lane] = bs - bv;
    }
    __syncthreads();
    if (t < NBK) {
        int excl = s - v + wbase[wv];
        lbase[t] = excl;
        hcur[t] = excl;
        gb[t] = v ? t * MAXB + gpos : 0;
    }
    __syncthreads();

    // LDS counting sort of the chunk by bucket
    #pragma unroll
    for (int u = 0; u < 3; ++u) {
        if (w2[u] != 0xFFFFFFFFu) {
            int b = w2[u] >> 22;
            int pos = atomicAdd(&hcur[b], 1);
            stg[pos] = (int)w2[u];
        }
    }
    __syncthreads();

    // coalesced global write in sorted order
    for (int i = t; i < ec; i += 1024) {
        unsigned int w = (unsigned)stg[i];
        int b = w >> 22;
        ebuf[gb[b] + (i - lbase[b])] = (int)(w & 0x3FFFFFu);
    }
}

// ---- phase 2: quarter-slab node sort + fp8 partial aggregation --------------
// 4 blocks per bucket (3128 blocks, ~12/CU queue): each sorts+gathers a quarter
// of the slab (avg 512 edges, per-node runs ~8 -> one predicated load batch per
// node) and writes a bf16 partial sum + u16 count. Shrinks the straggler tail.
#define ACC2(U)                                                              \
    {                                                                        \
        auto l0 = __builtin_amdgcn_cvt_pk_f32_fp8((int)(U).x, false);        \
        auto h0 = __builtin_amdgcn_cvt_pk_f32_fp8((int)(U).x, true);         \
        auto l1 = __builtin_amdgcn_cvt_pk_f32_fp8((int)(U).y, false);        \
        auto h1 = __builtin_amdgcn_cvt_pk_f32_fp8((int)(U).y, true);         \
        a0 += l0[0]; a1 += l0[1]; a2 += h0[0]; a3 += h0[1];                  \
        a4 += l1[0]; a5 += l1[1]; a6 += h1[0]; a7 += h1[1];                  \
    }

__global__ __launch_bounds__(512) void sortagg_k(const unsigned int* __restrict__ xb,
                                                 const int* __restrict__ ebuf,
                                                 const int* __restrict__ gcursor,
                                                 unsigned short* __restrict__ psb,
                                                 unsigned short* __restrict__ pcnt) {
    __shared__ int stg[QSLAB];                   // 2.6 KB
    __shared__ unsigned short srt[QSLAB];        // 1.3 KB
    __shared__ int cnt8[8][NPB];                 // 2 KB
    __shared__ int cur[NPB], off[NPB + 1];
    const int blk = blockIdx.x;
    const int b = blk >> 2, hb = blk & 3;
    const int t = threadIdx.x;
    const int wv = t >> 6, lane = t & 63;
    const int n = min(gcursor[b << 4], MAXB);
    const int g0 = (n * hb) >> 2, g1 = (n * (hb + 1)) >> 2;
    const int len = g1 - g0;
    const int* __restrict__ slab = ebuf + (size_t)b * MAXB + g0;

    // stage quarter-slab + wave-private histogram in one pass
    cnt8[wv][lane] = 0;
    for (int i = t; i < len; i += 512) {
        int v = slab[i];
        stg[i] = v;
        atomicAdd(&cnt8[wv][v & 63], 1);
    }
    __syncthreads();
    if (t < 64) {
        int v = 0;
        #pragma unroll
        for (int w = 0; w < 8; ++w) v += cnt8[w][t];
        int s = v;
        #pragma unroll
        for (int o = 1; o < 64; o <<= 1) {
            int u = __shfl_up(s, o);
            if (t >= o) s += u;
        }
        cur[t] = s - v;
        off[t] = s - v;
        if (t == 63) off[64] = s;
    }
    __syncthreads();
    for (int i = t; i < len; i += 512) {
        int w = stg[i];
        int pos = atomicAdd(&cur[w & 63], 1);
        srt[pos] = (unsigned short)(w >> 6);
    }
    __syncthreads();

    // gather + partial sum: uint2 per lane (16 lanes per edge-row)
    const int sub = lane >> 4, il2 = lane & 15;
    #pragma unroll
    for (int q = 0; q < 8; ++q) {
        int ln = wv + q * 8;                 // interleaved for degree balance
        int s0 = off[ln], s1 = off[ln + 1];
        float a0 = 0.f, a1 = 0.f, a2 = 0.f, a3 = 0.f;
        float a4 = 0.f, a5 = 0.f, a6 = 0.f, a7 = 0.f;
        int i = s0;
        for (; i + 16 <= s1; i += 16) {      // 4 uint2 in flight = 16 edges
            uint2 u[4];
            #pragma unroll
            for (int k = 0; k < 4; ++k)
                u[k] = ((const uint2*)xb)[(size_t)srt[i + 4 * k + sub] * 16 + il2];
            #pragma unroll
            for (int k = 0; k < 4; ++k) ACC2(u[k]);
        }
        if (i < s1) {                        // batched predicated tail (<=15 edges)
            uint2 u[4];
            #pragma unroll
            for (int k = 0; k < 4; ++k) {
                int e = i + 4 * k + sub;
                if (e < s1) u[k] = ((const uint2*)xb)[(size_t)srt[e] * 16 + il2];
                else { u[k].x = 0u; u[k].y = 0u; }
            }
            #pragma unroll
            for (int k = 0; k < 4; ++k) ACC2(u[k]);
        }
        // reduce across the 4 sub-groups (each holds same features)
        a0 += __shfl_xor(a0, 16); a0 += __shfl_xor(a0, 32);
        a1 += __shfl_xor(a1, 16); a1 += __shfl_xor(a1, 32);
        a2 += __shfl_xor(a2, 16); a2 += __shfl_xor(a2, 32);
        a3 += __shfl_xor(a3, 16); a3 += __shfl_xor(a3, 32);
        a4 += __shfl_xor(a4, 16); a4 += __shfl_xor(a4, 32);
        a5 += __shfl_xor(a5, 16); a5 += __shfl_xor(a5, 32);
        a6 += __shfl_xor(a6, 16); a6 += __shfl_xor(a6, 32);
        a7 += __shfl_xor(a7, 16); a7 += __shfl_xor(a7, 32);
        int node = b * NPB + ln;
        if (node < NN) {
            if (lane < 16) {
                short8 sv;
                sv[0] = (short)to_bf16(a0); sv[1] = (short)to_bf16(a1);
                sv[2] = (short)to_bf16(a2); sv[3] = (short)to_bf16(a3);
                sv[4] = (short)to_bf16(a4); sv[5] = (short)to_bf16(a5);
                sv[6] = (short)to_bf16(a6); sv[7] = (short)to_bf16(a7);
                *(short8*)&psb[((size_t)hb * NN + node) * DD + il2 * 8] = sv;
            }
            if (lane == 0) pcnt[hb * NN + node] = (unsigned short)(s1 - s0);
        }
    }
}

// ---- phase 3: MFMA epilogue out = (sum4(p)/deg) @ W^T + x @ B^T -------------
// 512 thr = 8 waves, 391 blocks of 128 rows (16 waves/CU).
__global__ __launch_bounds__(512) void gemm_mfma_k(const unsigned short* __restrict__ psb,
                                                   const unsigned short* __restrict__ pcnt,
                                                   const float* __restrict__ x,
                                                   const unsigned short* __restrict__ Wbf,
                                                   const unsigned short* __restrict__ Bbf,
                                                   float* __restrict__ out) {
    __shared__ unsigned short Wt[DD * WS];   // 34.8 KB
    __shared__ unsigned short Bt[DD * WS];   // 34.8 KB
    const int tid = threadIdx.x;
    #pragma unroll
    for (int it = 0; it < 8; ++it) {
        int idx = it * 512 + tid;            // 4096 ushort4 per matrix
        int n = idx >> 5;
        int k0 = (idx & 31) * 4;
        *(ushort4*)&Wt[n * WS + k0] = ((const ushort4*)Wbf)[idx];
        *(ushort4*)&Bt[n * WS + k0] = ((const ushort4*)Bbf)[idx];
    }
    __syncthreads();

    const int wave = tid >> 6;               // 0..7
    const int lane = tid & 63;
    const int m = lane & 15;
    const int quad = lane >> 4;
    const int rowA = min(blockIdx.x * 128 + wave * 16 + m, NN - 1);

    const float deg = (float)(pcnt[rowA] + pcnt[NN + rowA] +
                              pcnt[2 * NN + rowA] + pcnt[3 * NN + rowA]);
    const float inv = 1.0f / fmaxf(deg, 1.0f);

    f32x4 acc[8];
    #pragma unroll
    for (int nt = 0; nt < 8; ++nt) acc[nt] = (f32x4){0.f, 0.f, 0.f, 0.f};

    #pragma unroll
    for (int t = 0; t < 4; ++t) {
        const int k8 = t * 32 + quad * 8;
        // mean fragment: combine 4 bf16 partials in f32, single final round
        short8 p0 = *(const short8*)&psb[(size_t)rowA * DD + k8];
        short8 p1 = *(const short8*)&psb[((size_t)NN + rowA) * DD + k8];
        short8 p2 = *(const short8*)&psb[((size_t)2 * NN + rowA) * DD + k8];
        short8 p3 = *(const short8*)&psb[((size_t)3 * NN + rowA) * DD + k8];
        short8 mf;
        #pragma unroll
        for (int j = 0; j < 8; ++j) {
            float sm = (bf2f((unsigned short)p0[j]) + bf2f((unsigned short)p1[j])) +
                       (bf2f((unsigned short)p2[j]) + bf2f((unsigned short)p3[j]));
            mf[j] = (short)to_bf16(sm * inv);
        }

        float xv[8];
        {
            const float4* xq = (const float4*)&x[(size_t)rowA * DD + k8];
            float4 b0 = xq[0], b1 = xq[1];
            xv[0] = b0.x; xv[1] = b0.y; xv[2] = b0.z; xv[3] = b0.w;
            xv[4] = b1.x; xv[5] = b1.y; xv[6] = b1.z; xv[7] = b1.w;
        }
        short8 xh, xl;
        #pragma unroll
        for (int j = 0; j < 8; ++j) {
            unsigned short g = to_bf16(xv[j]);
            xh[j] = (short)g;
            xl[j] = (short)to_bf16(xv[j] - __uint_as_float((unsigned)g << 16));
        }
        #pragma unroll
        for (int nt = 0; nt < 8; ++nt) {
            int nrow = nt * 16 + m;
            short8 wf = *(const short8*)&Wt[nrow * WS + k8];
            short8 bf = *(const short8*)&Bt[nrow * WS + k8];
            acc[nt] = __builtin_amdgcn_mfma_f32_16x16x32_bf16(xl, bf, acc[nt], 0, 0, 0);
            acc[nt] = __builtin_amdgcn_mfma_f32_16x16x32_bf16(mf, wf, acc[nt], 0, 0, 0);
            acc[nt] = __builtin_amdgcn_mfma_f32_16x16x32_bf16(xh, bf, acc[nt], 0, 0, 0);
        }
    }

    // C/D layout: col = lane&15, row = quad*4 + reg (verified m89/m91)
    const int rowD0 = blockIdx.x * 128 + wave * 16 + quad * 4;
    #pragma unroll
    for (int nt = 0; nt < 8; ++nt) {
        #pragma unroll
        for (int r = 0; r < 4; ++r) {
            int row = rowD0 + r;
            if (row < NN) out[(size_t)row * DD + nt * 16 + m] = acc[nt][r];
        }
    }
}

extern "C" void kernel_launch(void* const* d_in, const int* in_sizes, int n_in,
                              void* d_out, int out_size, void* d_ws, size_t ws_size,
                              hipStream_t stream) {
    const float* x  = (const float*)d_in[0];
    const int*   ei = (const int*)d_in[1];   // [2, NE] int32
    const float* W  = (const float*)d_in[2];
    const float* Bm = (const float*)d_in[3];
    float* out = (float*)d_out;

    unsigned short* psb  = (unsigned short*)d_ws;                // NSPL*NN*DD bf16 (51.2 MB)
    unsigned int* xb     = (unsigned int*)(psb + (size_t)NSPL * NN * DD); // NN*32 uints
    int* ebuf            = (int*)(xb + (size_t)NN * 32);         // NBK*MAXB ints
    unsigned short* Wbf  = (unsigned short*)(ebuf + (size_t)NBK * MAXB); // DD*DD bf16
    unsigned short* Bbf  = Wbf + DD * DD;                        // DD*DD bf16
    unsigned short* pcnt = Bbf + DD * DD;                        // NSPL*NN u16
    int* gcursor         = (int*)(pcnt + (size_t)NSPL * NN);     // NBK*GCS ints (line-padded)

    hipMemsetAsync(gcursor, 0, NBK * GCS * sizeof(int), stream);
    convscatter_k<<<NCB, 1024, 0, stream>>>(ei, x, W, Bm, xb, Wbf, Bbf, gcursor, ebuf);
    sortagg_k<<<NBK * NSPL, 512, 0, stream>>>(xb, ebuf, gcursor, psb, pcnt);
    gemm_mfma_k<<<(NN + 127) / 128, 512, 0, stream>>>(psb, pcnt, x, Wbf, Bbf, out);
}

// Round 7
// 154.446 us; speedup vs baseline: 1.1907x; 1.1907x over previous
//
#include <hip/hip_runtime.h>
#include <hip/hip_bf16.h>

#define NN 50000
#define NE 1600000
#define DD 128
#define NPB 64                 // nodes per bucket (dst>>6)
#define NBK 782                // ceil(NN/64)
#define MAXB 2560              // bucket slab capacity (mean 2048, +11 sigma)
#define CHUNK 3072             // edges per convscatter block (2 blocks/CU shape)
#define NCB 521                // ceil(NE/CHUNK)
#define WS 136                 // gemm LDS row stride (bf16 elems): balanced banks

typedef __attribute__((ext_vector_type(8))) short short8;
typedef __attribute__((ext_vector_type(4))) float f32x4;

__device__ inline unsigned short to_bf16(float v) {
    __hip_bfloat16 h = __float2bfloat16(v);
    return __builtin_bit_cast(unsigned short, h);
}
__device__ inline float bf2f(unsigned short u) {
    return __uint_as_float((unsigned)u << 16);
}

// ---- phase 1: x->fp8 convert + W/B->bf16 convert + bucket-sorted scatter ----
// Round-5 verified form (155.3 us run): 521 blocks x 1024 thr.
__global__ __launch_bounds__(1024) void convscatter_k(const int* __restrict__ ei,
                                                      const float* __restrict__ x,
                                                      const float* __restrict__ W,
                                                      const float* __restrict__ Bm,
                                                      unsigned int* __restrict__ xb,
                                                      unsigned short* __restrict__ Wbf,
                                                      unsigned short* __restrict__ Bbf,
                                                      int* __restrict__ gcursor,
                                                      int* __restrict__ ebuf) {
    __shared__ int stg[CHUNK];        // 12 KB
    __shared__ int h[NBK];
    __shared__ int lbase[NBK];
    __shared__ int gb[NBK];
    __shared__ int hcur[NBK];
    __shared__ int wsum[16], wbase[16];
    const int t = threadIdx.x;
    const int lane = t & 63, wv = t >> 6;
    const int e0 = blockIdx.x * CHUNK;
    const int ec = min(CHUNK, NE - e0);

    for (int i = t; i < NBK; i += 1024) h[i] = 0;
    __syncthreads();

    unsigned int w2[3];
    #pragma unroll
    for (int u = 0; u < 3; ++u) {
        int i = u * 1024 + t;
        if (i < ec) {
            int src = ei[e0 + i];
            int dst = ei[NE + e0 + i];
            int b = dst >> 6;
            w2[u] = ((unsigned)b << 22) | ((unsigned)src << 6) | (unsigned)(dst & 63);
            atomicAdd(&h[b], 1);
        } else w2[u] = 0xFFFFFFFFu;
    }

    // independent: convert x (fp32) -> xb (packed 4x fp8-e4m3 per uint)
    {
        int gid = blockIdx.x * 1024 + t;
        const int total4 = NN * DD / 4;  // 1.6M float4 -> 1.6M uints
        for (int i = gid; i < total4; i += NCB * 1024) {
            float4 v = ((const float4*)x)[i];
            int p = __builtin_amdgcn_cvt_pk_fp8_f32(v.x, v.y, 0, false);
            p = __builtin_amdgcn_cvt_pk_fp8_f32(v.z, v.w, p, true);
            xb[i] = (unsigned)p;
        }
    }
    // independent: convert W,B (fp32) -> bf16, done by the underloaded last block
    if (blockIdx.x == NCB - 1) {
        for (int i = t; i < DD * DD / 4; i += 1024) {
            float4 w4 = ((const float4*)W)[i];
            float4 b4 = ((const float4*)Bm)[i];
            ushort4 wp, bp;
            wp.x = to_bf16(w4.x); wp.y = to_bf16(w4.y); wp.z = to_bf16(w4.z); wp.w = to_bf16(w4.w);
            bp.x = to_bf16(b4.x); bp.y = to_bf16(b4.y); bp.z = to_bf16(b4.z); bp.w = to_bf16(b4.w);
            ((ushort4*)Wbf)[i] = wp;
            ((ushort4*)Bbf)[i] = bp;
        }
    }
    __syncthreads();

    // hierarchical scan over NBK buckets (1 per thread, 2 barriers)
    int v = (t < NBK) ? h[t] : 0;
    int s = v;
    #pragma unroll
    for (int o = 1; o < 64; o <<= 1) {
        int u = __shfl_up(s, o);
        if (lane >= o) s += u;
    }
    if (lane == 63) wsum[wv] = s;
    __syncthreads();
    if (wv == 0 && lane < 16) {
        int bv = wsum[lane];
        int bs = bv;
        #pragma unroll
        for (int o = 1; o < 16; o <<= 1) {
            int u = __shfl_up(bs, o);
            if (lane >= o) bs += u;
        }
        wbase[lane] = bs - bv;
    }
    __syncthreads();
    if (t < NBK) {
        int excl = s - v + wbase[wv];
        lbase[t] = excl;
        hcur[t] = excl;
        gb[t] = v ? t * MAXB + atomicAdd(&gcursor[t], v) : 0;
    }
    __syncthreads();

    // LDS counting sort of the chunk by bucket
    #pragma unroll
    for (int u = 0; u < 3; ++u) {
        if (w2[u] != 0xFFFFFFFFu) {
            int b = w2[u] >> 22;
            int pos = atomicAdd(&hcur[b], 1);
            stg[pos] = (int)w2[u];
        }
    }
    __syncthreads();

    // coalesced global write in sorted order
    for (int i = t; i < ec; i += 1024) {
        unsigned int w = (unsigned)stg[i];
        int b = w >> 22;
        ebuf[gb[b] + (i - lbase[b])] = (int)(w & 0x3FFFFFu);
    }
}

// ---- phase 2: full-slab node sort + fp8 aggregation, 1024 thr ---------------
// One block per bucket (782 blocks, 16 waves): per-node fixed cost paid ONCE
// (round 6's 4-way split showed it dominates), single bf16 sum written
// (12.8 MB vs 25.6/51.2 for the split variants). Stage/hist/sort phases run
// at 1024-thread stride; 2 blocks/CU = full 32 waves/CU during the gather.
#define ACC2(U)                                                              \
    {                                                                        \
        auto l0 = __builtin_amdgcn_cvt_pk_f32_fp8((int)(U).x, false);        \
        auto h0 = __builtin_amdgcn_cvt_pk_f32_fp8((int)(U).x, true);         \
        auto l1 = __builtin_amdgcn_cvt_pk_f32_fp8((int)(U).y, false);        \
        auto h1 = __builtin_amdgcn_cvt_pk_f32_fp8((int)(U).y, true);         \
        a0 += l0[0]; a1 += l0[1]; a2 += h0[0]; a3 += h0[1];                  \
        a4 += l1[0]; a5 += l1[1]; a6 += h1[0]; a7 += h1[1];                  \
    }

__global__ __launch_bounds__(1024) void sortagg_k(const unsigned int* __restrict__ xb,
                                                  const int* __restrict__ ebuf,
                                                  const int* __restrict__ gcursor,
                                                  unsigned short* __restrict__ psb,
                                                  unsigned short* __restrict__ pcnt) {
    __shared__ int stg[MAXB];                    // 10.2 KB
    __shared__ unsigned short srt[MAXB];         // 5.1 KB
    __shared__ int cnt16[16][NPB];               // 4 KB (wave-private)
    __shared__ int cur[NPB], off[NPB + 1];
    const int b = blockIdx.x, t = threadIdx.x;
    const int wv = t >> 6, lane = t & 63;
    const int n = min(gcursor[b], MAXB);
    const int* __restrict__ slab = ebuf + (size_t)b * MAXB;

    // stage slab + wave-private histogram in one pass
    cnt16[wv][lane] = 0;
    for (int i = t; i < n; i += 1024) {
        int v = slab[i];
        stg[i] = v;
        atomicAdd(&cnt16[wv][v & 63], 1);
    }
    __syncthreads();
    if (t < 64) {
        int v = 0;
        #pragma unroll
        for (int w = 0; w < 16; ++w) v += cnt16[w][t];
        int s = v;
        #pragma unroll
        for (int o = 1; o < 64; o <<= 1) {
            int u = __shfl_up(s, o);
            if (t >= o) s += u;
        }
        cur[t] = s - v;
        off[t] = s - v;
        if (t == 63) off[64] = s;
    }
    __syncthreads();
    for (int i = t; i < n; i += 1024) {
        int w = stg[i];
        int pos = atomicAdd(&cur[w & 63], 1);
        srt[pos] = (unsigned short)(w >> 6);
    }
    __syncthreads();

    // gather + sum: uint2 per lane (16 lanes per edge-row, 4 edges per instr)
    const int sub = lane >> 4, il2 = lane & 15;
    #pragma unroll
    for (int q = 0; q < 4; ++q) {
        int ln = wv + q * 16;                // interleaved for degree balance
        int s0 = off[ln], s1 = off[ln + 1];
        float a0 = 0.f, a1 = 0.f, a2 = 0.f, a3 = 0.f;
        float a4 = 0.f, a5 = 0.f, a6 = 0.f, a7 = 0.f;
        int i = s0;
        for (; i + 16 <= s1; i += 16) {      // 4 uint2 in flight = 16 edges
            uint2 u[4];
            #pragma unroll
            for (int k = 0; k < 4; ++k)
                u[k] = ((const uint2*)xb)[(size_t)srt[i + 4 * k + sub] * 16 + il2];
            #pragma unroll
            for (int k = 0; k < 4; ++k) ACC2(u[k]);
        }
        if (i < s1) {                        // batched predicated tail (<=15 edges)
            uint2 u[4];
            #pragma unroll
            for (int k = 0; k < 4; ++k) {
                int e = i + 4 * k + sub;
                if (e < s1) u[k] = ((const uint2*)xb)[(size_t)srt[e] * 16 + il2];
                else { u[k].x = 0u; u[k].y = 0u; }
            }
            #pragma unroll
            for (int k = 0; k < 4; ++k) ACC2(u[k]);
        }
        // reduce across the 4 sub-groups (each holds same features)
        a0 += __shfl_xor(a0, 16); a0 += __shfl_xor(a0, 32);
        a1 += __shfl_xor(a1, 16); a1 += __shfl_xor(a1, 32);
        a2 += __shfl_xor(a2, 16); a2 += __shfl_xor(a2, 32);
        a3 += __shfl_xor(a3, 16); a3 += __shfl_xor(a3, 32);
        a4 += __shfl_xor(a4, 16); a4 += __shfl_xor(a4, 32);
        a5 += __shfl_xor(a5, 16); a5 += __shfl_xor(a5, 32);
        a6 += __shfl_xor(a6, 16); a6 += __shfl_xor(a6, 32);
        a7 += __shfl_xor(a7, 16); a7 += __shfl_xor(a7, 32);
        int node = b * NPB + ln;
        if (node < NN) {
            if (lane < 16) {
                short8 sv;
                sv[0] = (short)to_bf16(a0); sv[1] = (short)to_bf16(a1);
                sv[2] = (short)to_bf16(a2); sv[3] = (short)to_bf16(a3);
                sv[4] = (short)to_bf16(a4); sv[5] = (short)to_bf16(a5);
                sv[6] = (short)to_bf16(a6); sv[7] = (short)to_bf16(a7);
                *(short8*)&psb[(size_t)node * DD + il2 * 8] = sv;
            }
            if (lane == 0) pcnt[node] = (unsigned short)(s1 - s0);
        }
    }
}

// ---- phase 3: MFMA epilogue out = (sum/deg) @ W^T + x @ B^T -----------------
// 512 thr = 8 waves, 391 blocks of 128 rows (16 waves/CU).
__global__ __launch_bounds__(512) void gemm_mfma_k(const unsigned short* __restrict__ psb,
                                                   const unsigned short* __restrict__ pcnt,
                                                   const float* __restrict__ x,
                                                   const unsigned short* __restrict__ Wbf,
                                                   const unsigned short* __restrict__ Bbf,
                                                   float* __restrict__ out) {
    __shared__ unsigned short Wt[DD * WS];   // 34.8 KB
    __shared__ unsigned short Bt[DD * WS];   // 34.8 KB
    const int tid = threadIdx.x;
    #pragma unroll
    for (int it = 0; it < 8; ++it) {
        int idx = it * 512 + tid;            // 4096 ushort4 per matrix
        int n = idx >> 5;
        int k0 = (idx & 31) * 4;
        *(ushort4*)&Wt[n * WS + k0] = ((const ushort4*)Wbf)[idx];
        *(ushort4*)&Bt[n * WS + k0] = ((const ushort4*)Bbf)[idx];
    }
    __syncthreads();

    const int wave = tid >> 6;               // 0..7
    const int lane = tid & 63;
    const int m = lane & 15;
    const int quad = lane >> 4;
    const int rowA = min(blockIdx.x * 128 + wave * 16 + m, NN - 1);

    const float deg = (float)pcnt[rowA];
    const float inv = 1.0f / fmaxf(deg, 1.0f);

    f32x4 acc[8];
    #pragma unroll
    for (int nt = 0; nt < 8; ++nt) acc[nt] = (f32x4){0.f, 0.f, 0.f, 0.f};

    #pragma unroll
    for (int t = 0; t < 4; ++t) {
        const int k8 = t * 32 + quad * 8;
        // mean fragment: bf16 sum -> f32, divide, single final round
        short8 p0 = *(const short8*)&psb[(size_t)rowA * DD + k8];
        short8 mf;
        #pragma unroll
        for (int j = 0; j < 8; ++j)
            mf[j] = (short)to_bf16(bf2f((unsigned short)p0[j]) * inv);

        float xv[8];
        {
            const float4* xq = (const float4*)&x[(size_t)rowA * DD + k8];
            float4 b0 = xq[0], b1 = xq[1];
            xv[0] = b0.x; xv[1] = b0.y; xv[2] = b0.z; xv[3] = b0.w;
            xv[4] = b1.x; xv[5] = b1.y; xv[6] = b1.z; xv[7] = b1.w;
        }
        short8 xh, xl;
        #pragma unroll
        for (int j = 0; j < 8; ++j) {
            unsigned short g = to_bf16(xv[j]);
            xh[j] = (short)g;
            xl[j] = (short)to_bf16(xv[j] - __uint_as_float((unsigned)g << 16));
        }
        #pragma unroll
        for (int nt = 0; nt < 8; ++nt) {
            int nrow = nt * 16 + m;
            short8 wf = *(const short8*)&Wt[nrow * WS + k8];
            short8 bf = *(const short8*)&Bt[nrow * WS + k8];
            acc[nt] = __builtin_amdgcn_mfma_f32_16x16x32_bf16(xl, bf, acc[nt], 0, 0, 0);
            acc[nt] = __builtin_amdgcn_mfma_f32_16x16x32_bf16(mf, wf, acc[nt], 0, 0, 0);
            acc[nt] = __builtin_amdgcn_mfma_f32_16x16x32_bf16(xh, bf, acc[nt], 0, 0, 0);
        }
    }

    // C/D layout: col = lane&15, row = quad*4 + reg (verified m89/m91)
    const int rowD0 = blockIdx.x * 128 + wave * 16 + quad * 4;
    #pragma unroll
    for (int nt = 0; nt < 8; ++nt) {
        #pragma unroll
        for (int r = 0; r < 4; ++r) {
            int row = rowD0 + r;
            if (row < NN) out[(size_t)row * DD + nt * 16 + m] = acc[nt][r];
        }
    }
}

extern "C" void kernel_launch(void* const* d_in, const int* in_sizes, int n_in,
                              void* d_out, int out_size, void* d_ws, size_t ws_size,
                              hipStream_t stream) {
    const float* x  = (const float*)d_in[0];
    const int*   ei = (const int*)d_in[1];   // [2, NE] int32
    const float* W  = (const float*)d_in[2];
    const float* Bm = (const float*)d_in[3];
    float* out = (float*)d_out;

    unsigned short* psb  = (unsigned short*)d_ws;                // NN*DD bf16 (12.8 MB)
    unsigned int* xb     = (unsigned int*)(psb + (size_t)NN * DD); // NN*32 uints
    int* ebuf            = (int*)(xb + (size_t)NN * 32);         // NBK*MAXB ints
    unsigned short* Wbf  = (unsigned short*)(ebuf + (size_t)NBK * MAXB); // DD*DD bf16
    unsigned short* Bbf  = Wbf + DD * DD;                        // DD*DD bf16
    unsigned short* pcnt = Bbf + DD * DD;                        // NN u16
    int* gcursor         = (int*)(pcnt + (size_t)NN + (NN & 1)); // NBK ints

    hipMemsetAsync(gcursor, 0, NBK * sizeof(int), stream);
    convscatter_k<<<NCB, 1024, 0, stream>>>(ei, x, W, Bm, xb, Wbf, Bbf, gcursor, ebuf);
    sortagg_k<<<NBK, 1024, 0, stream>>>(xb, ebuf, gcursor, psb, pcnt);
    gemm_mfma_k<<<(NN + 127) / 128, 512, 0, stream>>>(psb, pcnt, x, Wbf, Bbf, out);
}